// Round 3
// baseline (387.553 us; speedup 1.0000x reference)
//
#include <hip/hip_runtime.h>
#include <math.h>

// FeatureWeightNet fused kernel v3 (MI355X / gfx950)
// B=2, C=64, H=512, W=640, NB=9, G=8.
// Thread = 4 consecutive pixels (one "quad") x 8 channels (one group).
// Block  = 256 threads = 32 quads (64x2 pixel tile) x 8 channel-groups.
// Grid   = 10 x 256 x 2 = 5120 blocks = 8 XCDs x 640 (bijective swizzle,
//          y-fastest within a column strip -> vertical halo reuse in L2).
// All tap column shifts are even -> 3 aligned float4 loads per stencil row
// serve wide(-4,0,4) AND narrow(-2,0,2) taps for 4 pixels; narrow taps use
// __builtin_shufflevector (compile-time register renaming, no copies).

typedef float f4 __attribute__((ext_vector_type(4)));

#define EPSV 1e-5f

__global__ __launch_bounds__(256, 4) void fwn_kernel(
    const float* __restrict__ F,    // [B,64,H,W]
    const float* __restrict__ off,  // [B,18,H,W]
    const float* __restrict__ w0, const float* __restrict__ b0,
    const float* __restrict__ g0, const float* __restrict__ beta0,
    const float* __restrict__ m0, const float* __restrict__ v0,
    const float* __restrict__ w1, const float* __restrict__ b1,
    const float* __restrict__ g1, const float* __restrict__ beta1,
    const float* __restrict__ m1, const float* __restrict__ v1,
    const float* __restrict__ ws, const float* __restrict__ bs,
    float* __restrict__ sig,        // [B,H,W]
    float* __restrict__ accp,       // [B,64,H,W]
    int H, int W)
{
    const int HW = H * W;

    // XCD-bijective swizzle: 5120 blocks = 8 * 640; y-fastest logical order.
    const int f = blockIdx.x;
    const int l = (f & 7) * 640 + (f >> 3);
    const int by = l & 255;          // y tile (2 rows)
    const int rest = l >> 8;         // 0..19
    const int bx = rest % 10;        // x tile (64 px)
    const int b  = rest / 10;        // batch

    const int tid = threadIdx.x;
    const int q  = tid & 31;         // quad: 16 in x, 2 in y
    const int cg = tid >> 5;         // channel group 0..7
    const int qx = q & 15, qy = q >> 4;
    const int w = bx * 64 + qx * 4;
    const int h = by * 2 + qy;

    // reflected rows for dy = {-4,-2,0,2,4}
    int rowoff[5];
    #pragma unroll
    for (int k = 0; k < 5; ++k) {
        int hh = h + 2 * k - 4;
        if (hh < 0) hh = -hh;
        if (hh >= H) hh = 2 * H - 2 - hh;
        rowoff[k] = hh * W;
    }

    const float* op = off + (size_t)b * 18 * HW + h * W + w;
    const float* Fb = F + (size_t)(b * 64 + cg * 8) * HW;
    float* ab = accp + (size_t)(b * 64 + cg * 8) * HW + h * W + w;

    f4 acc[8];
    #pragma unroll
    for (int i = 0; i < 8; ++i) acc[i] = (f4){0.f, 0.f, 0.f, 0.f};

    if (bx >= 1 && bx <= 8) {
        // ---------------- interior: aligned f4 loads ----------------
        #pragma unroll
        for (int r = 0; r < 5; ++r) {
            f4 wb[3], wn[3];
            if ((r & 1) == 0) {
                const int sy = r >> 1;
                #pragma unroll
                for (int sx = 0; sx < 3; ++sx)
                    wb[sx] = 0.5f * *(const f4*)(op + (size_t)(sy * 3 + sx) * HW);
            }
            if (r >= 1 && r <= 3) {
                const int sy = r - 1;
                #pragma unroll
                for (int sx = 0; sx < 3; ++sx)
                    wn[sx] = 0.5f * *(const f4*)(op + (size_t)(9 + sy * 3 + sx) * HW);
            }
            const int rbase = rowoff[r] + w - 4;
            #pragma unroll
            for (int i = 0; i < 8; ++i) {
                const float* cb = Fb + (size_t)i * HW + rbase;
                const f4 a0 = *(const f4*)(cb);
                const f4 a1 = *(const f4*)(cb + 4);
                const f4 a2 = *(const f4*)(cb + 8);
                if ((r & 1) == 0) {
                    acc[i] += wb[0] * a0;
                    acc[i] += wb[1] * a1;
                    acc[i] += wb[2] * a2;
                }
                if (r >= 1 && r <= 3) {
                    const f4 m0v = __builtin_shufflevector(a0, a1, 2, 3, 4, 5);
                    const f4 m2v = __builtin_shufflevector(a1, a2, 2, 3, 4, 5);
                    acc[i] += wn[0] * m0v;
                    acc[i] += wn[1] * a1;
                    acc[i] += wn[2] * m2v;
                }
            }
        }
    } else {
        // ---------------- border: reflected scalar gathers ----------------
        int colidx[12];
        #pragma unroll
        for (int j = 0; j < 12; ++j) {
            int x = w - 4 + j;
            if (x < 0) x = -x;
            if (x >= W) x = 2 * W - 2 - x;
            colidx[j] = x;
        }
        #pragma unroll
        for (int r = 0; r < 5; ++r) {
            f4 wb[3], wn[3];
            if ((r & 1) == 0) {
                const int sy = r >> 1;
                #pragma unroll
                for (int sx = 0; sx < 3; ++sx)
                    wb[sx] = 0.5f * *(const f4*)(op + (size_t)(sy * 3 + sx) * HW);
            }
            if (r >= 1 && r <= 3) {
                const int sy = r - 1;
                #pragma unroll
                for (int sx = 0; sx < 3; ++sx)
                    wn[sx] = 0.5f * *(const f4*)(op + (size_t)(9 + sy * 3 + sx) * HW);
            }
            #pragma unroll
            for (int i = 0; i < 8; ++i) {
                const float* cb = Fb + (size_t)i * HW + rowoff[r];
                float e[12];
                #pragma unroll
                for (int j = 0; j < 12; ++j) e[j] = cb[colidx[j]];
                if ((r & 1) == 0) {
                    #pragma unroll
                    for (int sx = 0; sx < 3; ++sx)
                        #pragma unroll
                        for (int p = 0; p < 4; ++p)
                            acc[i][p] += wb[sx][p] * e[4 * sx + p];
                }
                if (r >= 1 && r <= 3) {
                    #pragma unroll
                    for (int sx = 0; sx < 3; ++sx)
                        #pragma unroll
                        for (int p = 0; p < 4; ++p)
                            acc[i][p] += wn[sx][p] * e[2 + 2 * sx + p];
                }
            }
        }
    }

    // store acc (write-once stream, bypass L2) + in-thread group sum
    f4 gs = {0.f, 0.f, 0.f, 0.f};
    #pragma unroll
    for (int i = 0; i < 8; ++i) {
        __builtin_nontemporal_store(acc[i], (f4*)(ab + (size_t)i * HW));
        gs += acc[i];
    }

    __shared__ f4 xl[32][9];          // padded to 9 to break bank aliasing
    xl[q][cg] = gs * 0.125f;
    __syncthreads();

    // ---- fused BN+MLP head: one thread per quad ----
    if (tid < 32) {
        f4 sv;
        #pragma unroll
        for (int p = 0; p < 4; ++p) {
            float x[8];
            #pragma unroll
            for (int g = 0; g < 8; ++g) x[g] = xl[tid][g][p];
            float y0[16];
            #pragma unroll
            for (int o = 0; o < 16; ++o) {
                const float s0 = g0[o] * rsqrtf(v0[o] + EPSV);
                float z = 0.f;
                #pragma unroll
                for (int i = 0; i < 8; ++i) z += w0[o * 8 + i] * x[i];
                z = z * s0 + (b0[o] - m0[o]) * s0 + beta0[o];
                y0[o] = fmaxf(z, 0.f);
            }
            float y1[8];
            #pragma unroll
            for (int o = 0; o < 8; ++o) {
                const float s1 = g1[o] * rsqrtf(v1[o] + EPSV);
                float z = 0.f;
                #pragma unroll
                for (int i = 0; i < 16; ++i) z += w1[o * 16 + i] * y0[i];
                z = z * s1 + (b1[o] - m1[o]) * s1 + beta1[o];
                y1[o] = fmaxf(z, 0.f);
            }
            float sm = bs[0];
            #pragma unroll
            for (int i = 0; i < 8; ++i) sm += ws[i] * y1[i];
            sv[p] = 1.f / (1.f + __expf(-sm));
        }
        *(f4*)(sig + (size_t)b * HW + h * W + w) = sv;
    }
}

extern "C" void kernel_launch(void* const* d_in, const int* in_sizes, int n_in,
                              void* d_out, int out_size, void* d_ws, size_t ws_size,
                              hipStream_t stream) {
    const float* F    = (const float*)d_in[0];
    const float* off  = (const float*)d_in[1];
    const float* w0   = (const float*)d_in[2];
    const float* b0   = (const float*)d_in[3];
    const float* g0   = (const float*)d_in[4];
    const float* bt0  = (const float*)d_in[5];
    const float* m0   = (const float*)d_in[6];
    const float* v0   = (const float*)d_in[7];
    const float* w1   = (const float*)d_in[8];
    const float* b1   = (const float*)d_in[9];
    const float* g1   = (const float*)d_in[10];
    const float* bt1  = (const float*)d_in[11];
    const float* m1   = (const float*)d_in[12];
    const float* v1   = (const float*)d_in[13];
    const float* ws   = (const float*)d_in[14];
    const float* bs   = (const float*)d_in[15];

    const int B = 2, H = 512, W = 640;
    float* sig  = (float*)d_out;                  // [B,H,W]
    float* accp = sig + (size_t)B * H * W;        // [B,C,H,W]

    // grid: 10 x-tiles * 256 y-tiles * 2 batches = 5120 blocks (8 XCDs * 640)
    fwn_kernel<<<dim3(5120), dim3(256), 0, stream>>>(
        F, off, w0, b0, g0, bt0, m0, v0,
        w1, b1, g1, bt1, m1, v1, ws, bs,
        sig, accp, H, W);
}